// Round 1
// baseline (119.133 us; speedup 1.0000x reference)
//
#include <hip/hip_runtime.h>
#include <math.h>

// Problem constants (B,Tq,Tk,U) = (32,1024,1024,256), all f32 inputs, f32 out.
#define NB 32
#define TQ 1024
#define TK 1024
#define UD 256

// ---------------------------------------------------------------------------
// Kernel 1: sk[r] = sum_u v[u] * tanh( sum_c key[r,c] * Wq[u,c] )
//   rows r = b*TK + k, 32768 rows total. BM=64 rows/block, loop 4 u-tiles of
//   64, each over 4 k-chunks of 64. 16x16 threads, 4x4 register tile with
//   STRIDED ownership (row = ty+16i, u = tx+16j) so LDS b128 reads stay
//   conflict-free-ish with row stride 76 floats (304B = 19*16, so float4
//   aligned; consecutive rows 12 banks apart).
// ---------------------------------------------------------------------------
#define LDSTRIDE 76

__global__ __launch_bounds__(256) void sk_kernel(
    const float* __restrict__ key, const float* __restrict__ Wq,
    const float* __restrict__ v, float* __restrict__ sk) {
  __shared__ float As[64][LDSTRIDE];
  __shared__ float Bs[64][LDSTRIDE];
  const int row0 = blockIdx.x * 64;
  const int tid = threadIdx.x;
  const int tx = tid & 15, ty = tid >> 4;

  float srow[4] = {0.f, 0.f, 0.f, 0.f};

  for (int ut = 0; ut < 4; ++ut) {
    const int u0 = ut * 64;
    float acc[4][4];
#pragma unroll
    for (int i = 0; i < 4; ++i)
#pragma unroll
      for (int j = 0; j < 4; ++j) acc[i][j] = 0.f;

    for (int kc = 0; kc < 4; ++kc) {
      const int c0 = kc * 64;
      // Stage 64x64 tiles of key and Wq. 1024 float4 loads, 4 per thread.
#pragma unroll
      for (int f = 0; f < 4; ++f) {
        const int fl = tid + f * 256;        // 0..1023
        const int r = fl >> 4;               // 0..63
        const int c4 = (fl & 15) * 4;        // 0..60
        const float4 kv = *reinterpret_cast<const float4*>(
            &key[(size_t)(row0 + r) * UD + c0 + c4]);
        *reinterpret_cast<float4*>(&As[r][c4]) = kv;
        const float4 wv = *reinterpret_cast<const float4*>(
            &Wq[(size_t)(u0 + r) * UD + c0 + c4]);
        *reinterpret_cast<float4*>(&Bs[r][c4]) = wv;
      }
      __syncthreads();

#pragma unroll 4
      for (int kk = 0; kk < 64; kk += 4) {
        float4 a[4], b[4];
#pragma unroll
        for (int i = 0; i < 4; ++i)
          a[i] = *reinterpret_cast<const float4*>(&As[ty + 16 * i][kk]);
#pragma unroll
        for (int j = 0; j < 4; ++j)
          b[j] = *reinterpret_cast<const float4*>(&Bs[tx + 16 * j][kk]);
#pragma unroll
        for (int i = 0; i < 4; ++i)
#pragma unroll
          for (int j = 0; j < 4; ++j)
            acc[i][j] += a[i].x * b[j].x + a[i].y * b[j].y +
                         a[i].z * b[j].z + a[i].w * b[j].w;
      }
      __syncthreads();
    }

    // acc[i][j] = pre-tanh tk[row0+ty+16i][u0+tx+16j]; fold into srow.
#pragma unroll
    for (int j = 0; j < 4; ++j) {
      const float vj = v[u0 + tx + 16 * j];
#pragma unroll
      for (int i = 0; i < 4; ++i) srow[i] += vj * tanhf(acc[i][j]);
    }
  }

  // Reduce across tx (low 4 lane bits) within each wave.
#pragma unroll
  for (int i = 0; i < 4; ++i) {
    float s = srow[i];
    s += __shfl_xor(s, 1);
    s += __shfl_xor(s, 2);
    s += __shfl_xor(s, 4);
    s += __shfl_xor(s, 8);
    if (tx == 0) sk[row0 + ty + 16 * i] = s;
  }
}

// ---------------------------------------------------------------------------
// Kernel 2: masked softmax of sk rows -> attn. One block (256 thr) per batch.
//   valid_length==0  => all scores are the SAME fill (-1e6) => uniform 1/TK.
//   valid_length>0   => masked entries underflow to exactly 0 (matches ref).
// ---------------------------------------------------------------------------
__global__ __launch_bounds__(256) void attn_kernel(
    const float* __restrict__ sk, const int* __restrict__ vlen,
    float* __restrict__ attn) {
  const int b = blockIdx.x;
  const int tid = threadIdx.x;
  const int vl = vlen[b];
  const float* skb = sk + b * TK;
  float* ab = attn + b * TK;
  __shared__ float red[8];

  if (vl == 0) {
    const float u = 1.0f / (float)TK;
    for (int k = tid; k < TK; k += 256) ab[k] = u;
    return;
  }

  float m = -1e30f;
  for (int k = tid; k < TK; k += 256)
    if (k < vl) m = fmaxf(m, skb[k]);
  for (int off = 1; off < 64; off <<= 1) m = fmaxf(m, __shfl_xor(m, off));
  const int wid = tid >> 6;
  if ((tid & 63) == 0) red[wid] = m;
  __syncthreads();
  m = fmaxf(fmaxf(red[0], red[1]), fmaxf(red[2], red[3]));

  float e[4];
  float zs = 0.f;
#pragma unroll
  for (int idx = 0; idx < 4; ++idx) {
    const int k = tid + idx * 256;
    const float ee = (k < vl) ? expf(skb[k] - m) : 0.0f;
    e[idx] = ee;
    zs += ee;
  }
  for (int off = 1; off < 64; off <<= 1) zs += __shfl_xor(zs, off);
  if ((tid & 63) == 0) red[4 + wid] = zs;
  __syncthreads();
  zs = red[4] + red[5] + red[6] + red[7];
  const float rz = 1.0f / zs;
#pragma unroll
  for (int idx = 0; idx < 4; ++idx) ab[tid + idx * 256] = e[idx] * rz;
}

// ---------------------------------------------------------------------------
// Kernel 3: partial weighted sums over k-chunks.
//   part[b][ch][d] = sum_{k in chunk ch (64 wide)} attn[b,k]*value[b,k,d]
//   grid = 32*16 blocks, 256 threads (one per d).
// ---------------------------------------------------------------------------
__global__ __launch_bounds__(256) void pv_kernel(
    const float* __restrict__ attn, const float* __restrict__ value,
    float* __restrict__ part) {
  const int b = blockIdx.x >> 4;
  const int ch = blockIdx.x & 15;
  const int d = threadIdx.x;
  const float* vb = value + (size_t)b * TK * UD;
  const float* ab = attn + b * TK + ch * 64;
  float acc = 0.f;
#pragma unroll 4
  for (int k = 0; k < 64; ++k)
    acc = fmaf(ab[k], vb[(size_t)(ch * 64 + k) * UD + d], acc);
  part[(size_t)(b * 16 + ch) * UD + d] = acc;
}

// ---------------------------------------------------------------------------
// Kernel 4: reduce 16 partials -> out_row, broadcast over 64 q rows/block.
//   grid = 32*16 blocks, 256 threads; thread handles 4 consecutive d (float4),
//   writes 4 q-rows per iteration (4KB coalesced stores).
// ---------------------------------------------------------------------------
__global__ __launch_bounds__(256) void bcast_kernel(
    const float* __restrict__ part, float* __restrict__ out) {
  const int b = blockIdx.x >> 4;
  const int qc = blockIdx.x & 15;
  const int tid = threadIdx.x;
  const int qoff = tid >> 6;          // 0..3
  const int dd = (tid & 63) * 4;      // 0..252

  float4 s = make_float4(0.f, 0.f, 0.f, 0.f);
#pragma unroll
  for (int c = 0; c < 16; ++c) {
    const float4 p = *reinterpret_cast<const float4*>(
        &part[(size_t)(b * 16 + c) * UD + dd]);
    s.x += p.x; s.y += p.y; s.z += p.z; s.w += p.w;
  }

  float* ob = out + (size_t)b * TQ * UD + (size_t)qc * 64 * UD;
#pragma unroll 4
  for (int q4 = 0; q4 < 16; ++q4) {
    *reinterpret_cast<float4*>(&ob[(size_t)(q4 * 4 + qoff) * UD + dd]) = s;
  }
}

// ---------------------------------------------------------------------------
extern "C" void kernel_launch(void* const* d_in, const int* in_sizes, int n_in,
                              void* d_out, int out_size, void* d_ws,
                              size_t ws_size, hipStream_t stream) {
  // inputs: 0 query, 1 key, 2 value, 3 valid_length, 4 W_k, 5 W_q, 6 v
  const float* key = (const float*)d_in[1];
  const float* value = (const float*)d_in[2];
  const int* vlen = (const int*)d_in[3];
  const float* Wq = (const float*)d_in[5];
  const float* v = (const float*)d_in[6];
  float* out = (float*)d_out;

  char* ws = (char*)d_ws;
  float* sk = (float*)(ws);                     // 32768 f32 = 128 KB
  float* attn = (float*)(ws + (32768 * 4));     // 32768 f32 = 128 KB
  float* part = (float*)(ws + (65536 * 4));     // 32*16*256 f32 = 512 KB

  sk_kernel<<<(NB * TK) / 64, 256, 0, stream>>>(key, Wq, v, sk);
  attn_kernel<<<NB, 256, 0, stream>>>(sk, vlen, attn);
  pv_kernel<<<NB * 16, 256, 0, stream>>>(attn, value, part);
  bcast_kernel<<<NB * 16, 256, 0, stream>>>(part, out);
}

// Round 2
// 50.563 us; speedup vs baseline: 2.3561x; 2.3561x over previous
//
#include <hip/hip_runtime.h>
#include <hip/hip_fp16.h>
#include <math.h>

// (B,Tq,Tk,U) = (32,1024,1024,256), f32 in/out.
#define NB 32
#define TQ 1024
#define TK 1024
#define UD 256

typedef __attribute__((ext_vector_type(8))) _Float16 f16x8;
typedef __attribute__((ext_vector_type(4))) float f32x4;

// LDS tiles: A = 128 rows x 32 k f16 (64 B/row), B = 256 rows x 32 k f16.
// XOR swizzle spreads the 16B slot across banks: byte = (r*64 + s*16) ^ ((r&7)<<4).
__device__ __forceinline__ int lds_off(int r, int s) {
  return ((r << 6) + (s << 4)) ^ ((r & 7) << 4);
}

__device__ __forceinline__ float fast_tanh(float x) {
  const float e = __expf(2.0f * x);
  return 1.0f - 2.0f / (e + 1.0f);
}

// ---------------------------------------------------------------------------
// Kernel 1 (MFMA f16): sk[r] = sum_u v[u] * tanh( sum_c key[r,c] * Wq[u,c] )
// Block: 512 thr = 8 waves (2M x 4N). Tile: 128 rows x 256 u, K=256 in 8x32.
// ---------------------------------------------------------------------------
__global__ __launch_bounds__(512) void sk_mfma_kernel(
    const float* __restrict__ key, const float* __restrict__ Wq,
    const float* __restrict__ v, float* __restrict__ sk) {
  __shared__ __align__(16) char lds[8192 + 16384];  // A (8KB) then B (16KB)
  char* As = lds;
  char* Bs = lds + 8192;

  const int row0 = blockIdx.x * 128;
  const int tid = threadIdx.x;
  const int lane = tid & 63;
  const int wid = tid >> 6;  // 0..7
  const int wr = wid >> 2;   // 0..1 (M half)
  const int wc = wid & 3;    // 0..3 (u quarter)
  const int lx = lane & 15;  // row/col within fragment
  const int lg = lane >> 4;  // k-group (slot)

  // v values for this wave's u columns (n-frag n -> u = wc*64 + n*16 + lx)
  float vv[4];
#pragma unroll
  for (int n = 0; n < 4; ++n) vv[n] = v[wc * 64 + n * 16 + lx];

  f32x4 acc[4][4];
#pragma unroll
  for (int m = 0; m < 4; ++m)
#pragma unroll
    for (int n = 0; n < 4; ++n) acc[m][n] = (f32x4){0.f, 0.f, 0.f, 0.f};

  // staging assignment
  const int ar = tid >> 2;       // A row 0..127
  const int as = tid & 3;        // A 16B slot
  const int br = tid >> 1;       // B row (u) 0..255
  const int bs = (tid & 1) * 2;  // B slot base (writes bs, bs+1)

  for (int kc = 0; kc < 8; ++kc) {
    const int k0 = kc * 32;
    // ---- stage A: 8 f32 -> 8 f16, one b128 write ----
    {
      const float* g = &key[(size_t)(row0 + ar) * UD + k0 + as * 8];
      const float4 a0 = *reinterpret_cast<const float4*>(g);
      const float4 a1 = *reinterpret_cast<const float4*>(g + 4);
      f16x8 h;
      h[0] = (_Float16)a0.x; h[1] = (_Float16)a0.y;
      h[2] = (_Float16)a0.z; h[3] = (_Float16)a0.w;
      h[4] = (_Float16)a1.x; h[5] = (_Float16)a1.y;
      h[6] = (_Float16)a1.z; h[7] = (_Float16)a1.w;
      *reinterpret_cast<f16x8*>(As + lds_off(ar, as)) = h;
    }
    // ---- stage B: 16 f32 -> 16 f16, two b128 writes ----
    {
      const float* g = &Wq[(size_t)br * UD + k0 + bs * 8];
      const float4 b0 = *reinterpret_cast<const float4*>(g);
      const float4 b1 = *reinterpret_cast<const float4*>(g + 4);
      const float4 b2 = *reinterpret_cast<const float4*>(g + 8);
      const float4 b3 = *reinterpret_cast<const float4*>(g + 12);
      f16x8 h0, h1;
      h0[0] = (_Float16)b0.x; h0[1] = (_Float16)b0.y;
      h0[2] = (_Float16)b0.z; h0[3] = (_Float16)b0.w;
      h0[4] = (_Float16)b1.x; h0[5] = (_Float16)b1.y;
      h0[6] = (_Float16)b1.z; h0[7] = (_Float16)b1.w;
      h1[0] = (_Float16)b2.x; h1[1] = (_Float16)b2.y;
      h1[2] = (_Float16)b2.z; h1[3] = (_Float16)b2.w;
      h1[4] = (_Float16)b3.x; h1[5] = (_Float16)b3.y;
      h1[6] = (_Float16)b3.z; h1[7] = (_Float16)b3.w;
      *reinterpret_cast<f16x8*>(Bs + lds_off(br, bs)) = h0;
      *reinterpret_cast<f16x8*>(Bs + lds_off(br, bs + 1)) = h1;
    }
    __syncthreads();

    // ---- fragments + MFMA ----
    f16x8 af[4], bf[4];
#pragma unroll
    for (int m = 0; m < 4; ++m)
      af[m] = *reinterpret_cast<const f16x8*>(
          As + lds_off(wr * 64 + m * 16 + lx, lg));
#pragma unroll
    for (int n = 0; n < 4; ++n)
      bf[n] = *reinterpret_cast<const f16x8*>(
          Bs + lds_off(wc * 64 + n * 16 + lx, lg));
#pragma unroll
    for (int m = 0; m < 4; ++m)
#pragma unroll
      for (int n = 0; n < 4; ++n)
        acc[m][n] = __builtin_amdgcn_mfma_f32_16x16x32_f16(af[m], bf[n],
                                                           acc[m][n], 0, 0, 0);
    __syncthreads();
  }

  // ---- epilogue: tanh, dot with v, reduce ----
  // acc[m][n] reg r: row_local = wr*64 + m*16 + lg*4 + r ; u = wc*64+n*16+lx
  float* red = (float*)lds;  // [128][4]  (A region; safe after final barrier)

  float part[4][4];
#pragma unroll
  for (int m = 0; m < 4; ++m)
#pragma unroll
    for (int r = 0; r < 4; ++r) part[m][r] = 0.f;
#pragma unroll
  for (int m = 0; m < 4; ++m)
#pragma unroll
    for (int n = 0; n < 4; ++n)
#pragma unroll
      for (int r = 0; r < 4; ++r)
        part[m][r] += vv[n] * fast_tanh(acc[m][n][r]);

#pragma unroll
  for (int m = 0; m < 4; ++m)
#pragma unroll
    for (int r = 0; r < 4; ++r) {
      float s = part[m][r];
      s += __shfl_xor(s, 1);
      s += __shfl_xor(s, 2);
      s += __shfl_xor(s, 4);
      s += __shfl_xor(s, 8);
      if (lx == 0) red[(wr * 64 + m * 16 + lg * 4 + r) * 4 + wc] = s;
    }
  __syncthreads();
  if (tid < 128) {
    const float ssum =
        red[tid * 4 + 0] + red[tid * 4 + 1] + red[tid * 4 + 2] + red[tid * 4 + 3];
    sk[row0 + tid] = ssum;
  }
}

// ---------------------------------------------------------------------------
// Kernel 2: masked softmax of sk rows -> attn. One block (256 thr) per batch.
// ---------------------------------------------------------------------------
__global__ __launch_bounds__(256) void attn_kernel(
    const float* __restrict__ sk, const int* __restrict__ vlen,
    float* __restrict__ attn) {
  const int b = blockIdx.x;
  const int tid = threadIdx.x;
  const int vl = vlen[b];
  const float* skb = sk + b * TK;
  float* ab = attn + b * TK;
  __shared__ float red[8];

  if (vl == 0) {
    const float u = 1.0f / (float)TK;
    for (int k = tid; k < TK; k += 256) ab[k] = u;
    return;
  }

  float m = -1e30f;
  for (int k = tid; k < TK; k += 256)
    if (k < vl) m = fmaxf(m, skb[k]);
  for (int off = 1; off < 64; off <<= 1) m = fmaxf(m, __shfl_xor(m, off));
  const int wid = tid >> 6;
  if ((tid & 63) == 0) red[wid] = m;
  __syncthreads();
  m = fmaxf(fmaxf(red[0], red[1]), fmaxf(red[2], red[3]));

  float e[4];
  float zs = 0.f;
#pragma unroll
  for (int idx = 0; idx < 4; ++idx) {
    const int k = tid + idx * 256;
    const float ee = (k < vl) ? expf(skb[k] - m) : 0.0f;
    e[idx] = ee;
    zs += ee;
  }
  for (int off = 1; off < 64; off <<= 1) zs += __shfl_xor(zs, off);
  if ((tid & 63) == 0) red[4 + wid] = zs;
  __syncthreads();
  zs = red[4] + red[5] + red[6] + red[7];
  const float rz = 1.0f / zs;
#pragma unroll
  for (int idx = 0; idx < 4; ++idx) ab[tid + idx * 256] = e[idx] * rz;
}

// ---------------------------------------------------------------------------
// Kernel 3: part[b][ch][d] = sum_{k in 64-chunk ch} attn[b,k]*value[b,k,d]
// ---------------------------------------------------------------------------
__global__ __launch_bounds__(256) void pv_kernel(
    const float* __restrict__ attn, const float* __restrict__ value,
    float* __restrict__ part) {
  const int b = blockIdx.x >> 4;
  const int ch = blockIdx.x & 15;
  const int d = threadIdx.x;
  const float* vb = value + (size_t)b * TK * UD;
  const float* ab = attn + b * TK + ch * 64;
  float acc = 0.f;
#pragma unroll 4
  for (int k = 0; k < 64; ++k)
    acc = fmaf(ab[k], vb[(size_t)(ch * 64 + k) * UD + d], acc);
  part[(size_t)(b * 16 + ch) * UD + d] = acc;
}

// ---------------------------------------------------------------------------
// Kernel 4: reduce 16 partials -> out_row, broadcast over 64 q rows/block.
// ---------------------------------------------------------------------------
__global__ __launch_bounds__(256) void bcast_kernel(
    const float* __restrict__ part, float* __restrict__ out) {
  const int b = blockIdx.x >> 4;
  const int qc = blockIdx.x & 15;
  const int tid = threadIdx.x;
  const int qoff = tid >> 6;      // 0..3
  const int dd = (tid & 63) * 4;  // 0..252

  float4 s = make_float4(0.f, 0.f, 0.f, 0.f);
#pragma unroll
  for (int c = 0; c < 16; ++c) {
    const float4 p = *reinterpret_cast<const float4*>(
        &part[(size_t)(b * 16 + c) * UD + dd]);
    s.x += p.x; s.y += p.y; s.z += p.z; s.w += p.w;
  }

  float* ob = out + (size_t)b * TQ * UD + (size_t)qc * 64 * UD;
#pragma unroll 4
  for (int q4 = 0; q4 < 16; ++q4) {
    *reinterpret_cast<float4*>(&ob[(size_t)(q4 * 4 + qoff) * UD + dd]) = s;
  }
}

// ---------------------------------------------------------------------------
extern "C" void kernel_launch(void* const* d_in, const int* in_sizes, int n_in,
                              void* d_out, int out_size, void* d_ws,
                              size_t ws_size, hipStream_t stream) {
  // inputs: 0 query, 1 key, 2 value, 3 valid_length, 4 W_k, 5 W_q, 6 v
  const float* key = (const float*)d_in[1];
  const float* value = (const float*)d_in[2];
  const int* vlen = (const int*)d_in[3];
  const float* Wq = (const float*)d_in[5];
  const float* v = (const float*)d_in[6];
  float* out = (float*)d_out;

  char* ws = (char*)d_ws;
  float* sk = (float*)(ws);                  // 32768 f32 = 128 KB
  float* attn = (float*)(ws + (32768 * 4));  // 32768 f32 = 128 KB
  float* part = (float*)(ws + (65536 * 4));  // 32*16*256 f32 = 512 KB

  sk_mfma_kernel<<<(NB * TK) / 128, 512, 0, stream>>>(key, Wq, v, sk);
  attn_kernel<<<NB, 256, 0, stream>>>(sk, vlen, attn);
  pv_kernel<<<NB * 16, 256, 0, stream>>>(attn, value, part);
  bcast_kernel<<<NB * 16, 256, 0, stream>>>(part, out);
}

// Round 3
// 50.009 us; speedup vs baseline: 2.3822x; 1.0111x over previous
//
#include <hip/hip_runtime.h>
#include <hip/hip_fp16.h>
#include <math.h>

// (B,Tq,Tk,U) = (32,1024,1024,256), f32 in/out.
#define NB 32
#define TQ 1024
#define TK 1024
#define UD 256

typedef __attribute__((ext_vector_type(8))) _Float16 f16x8;
typedef __attribute__((ext_vector_type(4))) _Float16 f16x4;
typedef __attribute__((ext_vector_type(4))) float f32x4;

// A-tile LDS: 64 rows x 32 k f16 (64B/row), 16B slots, XOR swizzle.
__device__ __forceinline__ int lds_off(int r, int s) {
  return ((r << 6) + (s << 4)) ^ ((r & 7) << 4);
}

__device__ __forceinline__ float fast_tanh(float x) {
  const float e = __expf(2.0f * x);
  return 1.0f - 2.0f / (e + 1.0f);
}

// ---------------------------------------------------------------------------
// Kernel 0: Wq f32 -> f16 once (128 KB out, L2-resident for sk kernel).
// ---------------------------------------------------------------------------
__global__ __launch_bounds__(256) void cvt_wq_kernel(
    const float* __restrict__ Wq, _Float16* __restrict__ wq16) {
  const int i = (blockIdx.x * 256 + threadIdx.x) * 4;
  const float4 w = *reinterpret_cast<const float4*>(Wq + i);
  f16x4 h;
  h[0] = (_Float16)w.x; h[1] = (_Float16)w.y;
  h[2] = (_Float16)w.z; h[3] = (_Float16)w.w;
  *reinterpret_cast<f16x4*>(wq16 + i) = h;
}

// ---------------------------------------------------------------------------
// Kernel 1 (MFMA f16): sk[r] = sum_u v[u] * tanh( sum_c key[r,c] * Wq[u,c] )
// 256 thr = 4 waves (1M x 4N). Tile 64 rows x 256 u, K in 8x32 steps.
// A: reg-staged f32->f16 into double-buffered swizzled LDS (prefetch +1).
// B: f16 fragments loaded straight from global (L2-hot wq16), prefetch +1.
// ---------------------------------------------------------------------------
__global__ __launch_bounds__(256) void sk_mfma_kernel(
    const float* __restrict__ key, const _Float16* __restrict__ wq16,
    const float* __restrict__ v, float* __restrict__ sk) {
  __shared__ __align__(16) char lds[2 * 4096];

  const int row0 = blockIdx.x * 64;
  const int tid = threadIdx.x;
  const int lane = tid & 63;
  const int wc = tid >> 6;   // wave = u quarter (0..3)
  const int lx = lane & 15;
  const int lg = lane >> 4;

  float vv[4];
#pragma unroll
  for (int n = 0; n < 4; ++n) vv[n] = v[wc * 64 + n * 16 + lx];

  f32x4 acc[4][4];
#pragma unroll
  for (int m = 0; m < 4; ++m)
#pragma unroll
    for (int n = 0; n < 4; ++n) acc[m][n] = (f32x4){0.f, 0.f, 0.f, 0.f};

  // A staging: thread -> (row, 16B slot)
  const int ar = tid >> 2, as = tid & 3;
  const float* gA = &key[(size_t)(row0 + ar) * UD + as * 8];

  // B fragment pointers (per n)
  const _Float16* gB[4];
#pragma unroll
  for (int n = 0; n < 4; ++n)
    gB[n] = wq16 + (size_t)(wc * 64 + n * 16 + lx) * UD + lg * 8;

  // prologue: kc=0 prefetch
  float4 a0 = *reinterpret_cast<const float4*>(gA);
  float4 a1 = *reinterpret_cast<const float4*>(gA + 4);
  f16x8 bfrag[2][4];
#pragma unroll
  for (int n = 0; n < 4; ++n)
    bfrag[0][n] = *reinterpret_cast<const f16x8*>(gB[n]);

#pragma unroll
  for (int kc = 0; kc < 8; ++kc) {
    const int cur = kc & 1;
    // convert + write A tile
    f16x8 h;
    h[0] = (_Float16)a0.x; h[1] = (_Float16)a0.y;
    h[2] = (_Float16)a0.z; h[3] = (_Float16)a0.w;
    h[4] = (_Float16)a1.x; h[5] = (_Float16)a1.y;
    h[6] = (_Float16)a1.z; h[7] = (_Float16)a1.w;
    *reinterpret_cast<f16x8*>(lds + cur * 4096 + lds_off(ar, as)) = h;
    // prefetch next A + B
    if (kc < 7) {
      const int kn = (kc + 1) * 32;
      a0 = *reinterpret_cast<const float4*>(gA + kn);
      a1 = *reinterpret_cast<const float4*>(gA + kn + 4);
#pragma unroll
      for (int n = 0; n < 4; ++n)
        bfrag[(kc + 1) & 1][n] =
            *reinterpret_cast<const f16x8*>(gB[n] + kn);
    }
    __syncthreads();
    f16x8 af[4];
#pragma unroll
    for (int m = 0; m < 4; ++m)
      af[m] = *reinterpret_cast<const f16x8*>(
          lds + cur * 4096 + lds_off(m * 16 + lx, lg));
#pragma unroll
    for (int m = 0; m < 4; ++m)
#pragma unroll
      for (int n = 0; n < 4; ++n)
        acc[m][n] = __builtin_amdgcn_mfma_f32_16x16x32_f16(
            af[m], bfrag[cur][n], acc[m][n], 0, 0, 0);
  }

  // epilogue: tanh, dot v, reduce over u.
  // acc[m][n] reg r: row_local = m*16 + lg*4 + r ; u = wc*64 + n*16 + lx
  float* red = (float*)lds;  // buffer0 region; all waves done with it

  float part[4][4];
#pragma unroll
  for (int m = 0; m < 4; ++m)
#pragma unroll
    for (int r = 0; r < 4; ++r) part[m][r] = 0.f;
#pragma unroll
  for (int m = 0; m < 4; ++m)
#pragma unroll
    for (int n = 0; n < 4; ++n)
#pragma unroll
      for (int r = 0; r < 4; ++r)
        part[m][r] += vv[n] * fast_tanh(acc[m][n][r]);

#pragma unroll
  for (int m = 0; m < 4; ++m)
#pragma unroll
    for (int r = 0; r < 4; ++r) {
      float s = part[m][r];
      s += __shfl_xor(s, 1);
      s += __shfl_xor(s, 2);
      s += __shfl_xor(s, 4);
      s += __shfl_xor(s, 8);
      if (lx == 0) red[(m * 16 + lg * 4 + r) * 4 + wc] = s;
    }
  __syncthreads();
  if (tid < 64) {
    sk[row0 + tid] = red[tid * 4 + 0] + red[tid * 4 + 1] +
                     red[tid * 4 + 2] + red[tid * 4 + 3];
  }
}

// ---------------------------------------------------------------------------
// Kernel 2 (fused softmax + PV partial): block (b,ch). Each block redundantly
// computes its batch's masked softmax stats from sk (4KB, L2-hot), then
// part[b][ch][d] = sum_{k in 64-chunk} w[k]*value[b,k,d] with float4 loads.
// ---------------------------------------------------------------------------
__global__ __launch_bounds__(256) void pv_kernel(
    const float* __restrict__ sk, const int* __restrict__ vlen,
    const float* __restrict__ value, float* __restrict__ part) {
  const int b = blockIdx.x >> 4;
  const int ch = blockIdx.x & 15;
  const int tid = threadIdx.x;
  const int vl = vlen[b];
  __shared__ float wbuf[64];
  __shared__ float red4[8];
  __shared__ float racc[1024];
  const float* skb = sk + b * TK;

  if (vl == 0) {  // uniform softmax over the constant-fill row
    if (tid < 64) wbuf[tid] = 1.0f / (float)TK;
  } else {
    float m = -1e30f;
#pragma unroll
    for (int idx = 0; idx < 4; ++idx) {
      const int k = tid + idx * 256;
      if (k < vl) m = fmaxf(m, skb[k]);
    }
    for (int off = 1; off < 64; off <<= 1) m = fmaxf(m, __shfl_xor(m, off));
    if ((tid & 63) == 0) red4[tid >> 6] = m;
    __syncthreads();
    m = fmaxf(fmaxf(red4[0], red4[1]), fmaxf(red4[2], red4[3]));
    float zs = 0.f;
#pragma unroll
    for (int idx = 0; idx < 4; ++idx) {
      const int k = tid + idx * 256;
      zs += (k < vl) ? expf(skb[k] - m) : 0.f;
    }
    for (int off = 1; off < 64; off <<= 1) zs += __shfl_xor(zs, off);
    if ((tid & 63) == 0) red4[4 + (tid >> 6)] = zs;
    __syncthreads();
    const float rz = 1.0f / (red4[4] + red4[5] + red4[6] + red4[7]);
    if (tid < 64) {
      const int k = ch * 64 + tid;
      wbuf[tid] = (k < vl) ? expf(skb[k] - m) * rz : 0.f;
    }
  }
  __syncthreads();

  const int ko = tid >> 6;
  const int dl = (tid & 63) * 4;
  const float* vb = value + ((size_t)b * TK + ch * 64) * UD;
  float4 a = make_float4(0.f, 0.f, 0.f, 0.f);
#pragma unroll 4
  for (int kk = ko; kk < 64; kk += 4) {
    const float wk = wbuf[kk];
    const float4 x = *reinterpret_cast<const float4*>(vb + (size_t)kk * UD + dl);
    a.x = fmaf(wk, x.x, a.x);
    a.y = fmaf(wk, x.y, a.y);
    a.z = fmaf(wk, x.z, a.z);
    a.w = fmaf(wk, x.w, a.w);
  }
  *reinterpret_cast<float4*>(&racc[ko * 256 + dl]) = a;
  __syncthreads();
  const float s =
      racc[tid] + racc[256 + tid] + racc[512 + tid] + racc[768 + tid];
  part[(size_t)(b * 16 + ch) * UD + tid] = s;
}

// ---------------------------------------------------------------------------
// Kernel 3: reduce 16 partials -> out_row, broadcast over 64 q rows/block.
// ---------------------------------------------------------------------------
__global__ __launch_bounds__(256) void bcast_kernel(
    const float* __restrict__ part, float* __restrict__ out) {
  const int b = blockIdx.x >> 4;
  const int qc = blockIdx.x & 15;
  const int tid = threadIdx.x;
  const int qoff = tid >> 6;      // 0..3
  const int dd = (tid & 63) * 4;  // 0..252

  float4 s = make_float4(0.f, 0.f, 0.f, 0.f);
#pragma unroll
  for (int c = 0; c < 16; ++c) {
    const float4 p = *reinterpret_cast<const float4*>(
        &part[(size_t)(b * 16 + c) * UD + dd]);
    s.x += p.x; s.y += p.y; s.z += p.z; s.w += p.w;
  }

  float* ob = out + (size_t)b * TQ * UD + (size_t)qc * 64 * UD;
#pragma unroll 4
  for (int q4 = 0; q4 < 16; ++q4) {
    *reinterpret_cast<float4*>(&ob[(size_t)(q4 * 4 + qoff) * UD + dd]) = s;
  }
}

// ---------------------------------------------------------------------------
extern "C" void kernel_launch(void* const* d_in, const int* in_sizes, int n_in,
                              void* d_out, int out_size, void* d_ws,
                              size_t ws_size, hipStream_t stream) {
  // inputs: 0 query, 1 key, 2 value, 3 valid_length, 4 W_k, 5 W_q, 6 v
  const float* key = (const float*)d_in[1];
  const float* value = (const float*)d_in[2];
  const int* vlen = (const int*)d_in[3];
  const float* Wq = (const float*)d_in[5];
  const float* v = (const float*)d_in[6];
  float* out = (float*)d_out;

  char* ws = (char*)d_ws;
  _Float16* wq16 = (_Float16*)(ws);             // 64K f16 = 128 KB
  float* sk = (float*)(ws + 131072);            // 32768 f32 = 128 KB
  float* part = (float*)(ws + 262144);          // 32*16*256 f32 = 512 KB

  cvt_wq_kernel<<<64, 256, 0, stream>>>(Wq, wq16);
  sk_mfma_kernel<<<(NB * TK) / 64, 256, 0, stream>>>(key, wq16, v, sk);
  pv_kernel<<<NB * 16, 256, 0, stream>>>(sk, vlen, value, part);
  bcast_kernel<<<NB * 16, 256, 0, stream>>>(part, out);
}

// Round 4
// 48.789 us; speedup vs baseline: 2.4418x; 1.0250x over previous
//
#include <hip/hip_runtime.h>
#include <hip/hip_fp16.h>
#include <math.h>

// (B,Tq,Tk,U) = (32,1024,1024,256), f32 in/out.
#define NB 32
#define TQ 1024
#define TK 1024
#define UD 256

typedef __attribute__((ext_vector_type(8))) _Float16 f16x8;
typedef __attribute__((ext_vector_type(4))) float f32x4;

__device__ __forceinline__ float fast_tanh(float x) {
  const float e = __expf(2.0f * x);
  return 1.0f - 2.0f / (e + 1.0f);
}

// ---------------------------------------------------------------------------
// K0: Wq f32 -> f16 in k-slot-major layout: wq16t[ks][u][j] (ks=k>>3, j=k&7).
// 32 blocks x 256 thr, one (u, ks) pair per thread.
// ---------------------------------------------------------------------------
__global__ __launch_bounds__(256) void cvt_wq_kernel(
    const float* __restrict__ Wq, _Float16* __restrict__ wq16t) {
  const int idx = blockIdx.x * 256 + threadIdx.x;  // 8192
  const int u = idx >> 5;
  const int ks = idx & 31;
  const float4 w0 = *reinterpret_cast<const float4*>(Wq + u * UD + ks * 8);
  const float4 w1 = *reinterpret_cast<const float4*>(Wq + u * UD + ks * 8 + 4);
  f16x8 h;
  h[0] = (_Float16)w0.x; h[1] = (_Float16)w0.y;
  h[2] = (_Float16)w0.z; h[3] = (_Float16)w0.w;
  h[4] = (_Float16)w1.x; h[5] = (_Float16)w1.y;
  h[6] = (_Float16)w1.z; h[7] = (_Float16)w1.w;
  *reinterpret_cast<f16x8*>(wq16t + ((size_t)ks * 256 + u) * 8) = h;
}

// ---------------------------------------------------------------------------
// K1: sk[r] = sum_u v[u] * tanh( sum_c key[r,c] * Wq[u,c] )   (MFMA f16)
// 512 blocks x 256 thr (4 waves). Wave owns 16 rows x all 256 u.
// B: full Wq panel in 64 KB LDS, staged in 2 phases of k=128 (linear copy
//    from k-slot-major wq16t; only 4 barriers in the whole kernel).
// A: global->register, lane(lx,lg) = row lx, k-slot lg (fragment-native).
// K-loop is barrier-free -> compiler uses counted vmcnt, pipelines loads.
// ---------------------------------------------------------------------------
__global__ __launch_bounds__(256, 2) void sk_mfma_kernel(
    const float* __restrict__ key, const _Float16* __restrict__ wq16t,
    const float* __restrict__ v, float* __restrict__ sk) {
  __shared__ _Float16 Bt[32768];  // 64 KB: [16 ks][256 u][8 j]

  const int tid = threadIdx.x;
  const int lane = tid & 63;
  const int wc = tid >> 6;   // wave 0..3 -> row group
  const int lx = lane & 15;
  const int lg = lane >> 4;
  const int arow = blockIdx.x * 64 + wc * 16 + lx;
  const float* gA = key + (size_t)arow * UD + lg * 8;

  f32x4 acc[16];
#pragma unroll
  for (int n = 0; n < 16; ++n) acc[n] = (f32x4){0.f, 0.f, 0.f, 0.f};

#pragma unroll
  for (int p = 0; p < 2; ++p) {
    // stage 64 KB of B for k in [p*128, p*128+128): linear copy
    {
      const f16x8* src =
          reinterpret_cast<const f16x8*>(wq16t + (size_t)p * 32768) + tid;
      f16x8* dst = reinterpret_cast<f16x8*>(Bt) + tid;
#pragma unroll
      for (int it = 0; it < 16; ++it) dst[it * 256] = src[it * 256];
    }
    __syncthreads();

#pragma unroll
    for (int kc = 0; kc < 4; ++kc) {
      const int k0 = p * 128 + kc * 32;
      const float4 a0 = *reinterpret_cast<const float4*>(gA + k0);
      const float4 a1 = *reinterpret_cast<const float4*>(gA + k0 + 4);
      f16x8 af;
      af[0] = (_Float16)a0.x; af[1] = (_Float16)a0.y;
      af[2] = (_Float16)a0.z; af[3] = (_Float16)a0.w;
      af[4] = (_Float16)a1.x; af[5] = (_Float16)a1.y;
      af[6] = (_Float16)a1.z; af[7] = (_Float16)a1.w;
#pragma unroll
      for (int n = 0; n < 16; ++n) {
        const f16x8 bf = *reinterpret_cast<const f16x8*>(
            Bt + (((kc * 4 + lg) * 256) + n * 16 + lx) * 8);
        acc[n] =
            __builtin_amdgcn_mfma_f32_16x16x32_f16(af, bf, acc[n], 0, 0, 0);
      }
    }
    __syncthreads();
  }

  // Epilogue: tanh, dot v over u=(n,lx), shfl-reduce over lx, store.
  // C layout: row_local = lg*4 + r, col(u_local) = lx.
  float out_r[4] = {0.f, 0.f, 0.f, 0.f};
#pragma unroll
  for (int n = 0; n < 16; ++n) {
    const float vn = v[n * 16 + lx];
#pragma unroll
    for (int r = 0; r < 4; ++r) out_r[r] += vn * fast_tanh(acc[n][r]);
  }
#pragma unroll
  for (int r = 0; r < 4; ++r) {
    float s = out_r[r];
    s += __shfl_xor(s, 1);
    s += __shfl_xor(s, 2);
    s += __shfl_xor(s, 4);
    s += __shfl_xor(s, 8);
    if (lx == 0) sk[blockIdx.x * 64 + wc * 16 + lg * 4 + r] = s;
  }
}

// ---------------------------------------------------------------------------
// K2 (fused softmax + PV partial): block (b,ch). Redundant per-block softmax
// stats from sk (4KB, L2-hot), then 64-k chunk of attn @ value with float4.
// ---------------------------------------------------------------------------
__global__ __launch_bounds__(256) void pv_kernel(
    const float* __restrict__ sk, const int* __restrict__ vlen,
    const float* __restrict__ value, float* __restrict__ part) {
  const int b = blockIdx.x >> 4;
  const int ch = blockIdx.x & 15;
  const int tid = threadIdx.x;
  const int vl = vlen[b];
  __shared__ float wbuf[64];
  __shared__ float red4[8];
  __shared__ float racc[1024];
  const float* skb = sk + b * TK;

  if (vl == 0) {  // uniform softmax over the constant-fill row
    if (tid < 64) wbuf[tid] = 1.0f / (float)TK;
  } else {
    float m = -1e30f;
#pragma unroll
    for (int idx = 0; idx < 4; ++idx) {
      const int k = tid + idx * 256;
      if (k < vl) m = fmaxf(m, skb[k]);
    }
    for (int off = 1; off < 64; off <<= 1) m = fmaxf(m, __shfl_xor(m, off));
    if ((tid & 63) == 0) red4[tid >> 6] = m;
    __syncthreads();
    m = fmaxf(fmaxf(red4[0], red4[1]), fmaxf(red4[2], red4[3]));
    float zs = 0.f;
#pragma unroll
    for (int idx = 0; idx < 4; ++idx) {
      const int k = tid + idx * 256;
      zs += (k < vl) ? __expf(skb[k] - m) : 0.f;
    }
    for (int off = 1; off < 64; off <<= 1) zs += __shfl_xor(zs, off);
    if ((tid & 63) == 0) red4[4 + (tid >> 6)] = zs;
    __syncthreads();
    const float rz = 1.0f / (red4[4] + red4[5] + red4[6] + red4[7]);
    if (tid < 64) {
      const int k = ch * 64 + tid;
      wbuf[tid] = (k < vl) ? __expf(skb[k] - m) * rz : 0.f;
    }
  }
  __syncthreads();

  const int ko = tid >> 6;
  const int dl = (tid & 63) * 4;
  const float* vb = value + ((size_t)b * TK + ch * 64) * UD;
  float4 a = make_float4(0.f, 0.f, 0.f, 0.f);
#pragma unroll 4
  for (int kk = ko; kk < 64; kk += 4) {
    const float wk = wbuf[kk];
    const float4 x =
        *reinterpret_cast<const float4*>(vb + (size_t)kk * UD + dl);
    a.x = fmaf(wk, x.x, a.x);
    a.y = fmaf(wk, x.y, a.y);
    a.z = fmaf(wk, x.z, a.z);
    a.w = fmaf(wk, x.w, a.w);
  }
  *reinterpret_cast<float4*>(&racc[ko * 256 + dl]) = a;
  __syncthreads();
  const float s =
      racc[tid] + racc[256 + tid] + racc[512 + tid] + racc[768 + tid];
  part[(size_t)(b * 16 + ch) * UD + tid] = s;
}

// ---------------------------------------------------------------------------
// K3: reduce 16 partials -> out_row, broadcast over 64 q rows/block.
// ---------------------------------------------------------------------------
__global__ __launch_bounds__(256) void bcast_kernel(
    const float* __restrict__ part, float* __restrict__ out) {
  const int b = blockIdx.x >> 4;
  const int qc = blockIdx.x & 15;
  const int tid = threadIdx.x;
  const int qoff = tid >> 6;      // 0..3
  const int dd = (tid & 63) * 4;  // 0..252

  float4 s = make_float4(0.f, 0.f, 0.f, 0.f);
#pragma unroll
  for (int c = 0; c < 16; ++c) {
    const float4 p = *reinterpret_cast<const float4*>(
        &part[(size_t)(b * 16 + c) * UD + dd]);
    s.x += p.x; s.y += p.y; s.z += p.z; s.w += p.w;
  }

  float* ob = out + (size_t)b * TQ * UD + (size_t)qc * 64 * UD;
#pragma unroll 4
  for (int q4 = 0; q4 < 16; ++q4) {
    *reinterpret_cast<float4*>(&ob[(size_t)(q4 * 4 + qoff) * UD + dd]) = s;
  }
}

// ---------------------------------------------------------------------------
extern "C" void kernel_launch(void* const* d_in, const int* in_sizes, int n_in,
                              void* d_out, int out_size, void* d_ws,
                              size_t ws_size, hipStream_t stream) {
  // inputs: 0 query, 1 key, 2 value, 3 valid_length, 4 W_k, 5 W_q, 6 v
  const float* key = (const float*)d_in[1];
  const float* value = (const float*)d_in[2];
  const int* vlen = (const int*)d_in[3];
  const float* Wq = (const float*)d_in[5];
  const float* v = (const float*)d_in[6];
  float* out = (float*)d_out;

  char* ws = (char*)d_ws;
  _Float16* wq16t = (_Float16*)(ws);    // 64K f16 = 128 KB (k-slot-major)
  float* sk = (float*)(ws + 131072);    // 32768 f32 = 128 KB
  float* part = (float*)(ws + 262144);  // 32*16*256 f32 = 512 KB

  cvt_wq_kernel<<<32, 256, 0, stream>>>(Wq, wq16t);
  sk_mfma_kernel<<<(NB * TK) / 64, 256, 0, stream>>>(key, wq16t, v, sk);
  pv_kernel<<<NB * 16, 256, 0, stream>>>(sk, vlen, value, part);
  bcast_kernel<<<NB * 16, 256, 0, stream>>>(part, out);
}

// Round 6
// 43.791 us; speedup vs baseline: 2.7205x; 1.1141x over previous
//
#include <hip/hip_runtime.h>
#include <hip/hip_fp16.h>
#include <math.h>

// (B,Tq,Tk,U) = (32,1024,1024,256), f32 in/out.
#define NB 32
#define TQ 1024
#define TK 1024
#define UD 256

typedef __attribute__((ext_vector_type(8))) _Float16 f16x8;
typedef __attribute__((ext_vector_type(4))) float f32x4;

__device__ __forceinline__ float fast_tanh(float x) {
  const float e = __expf(2.0f * x);
  return 1.0f - 2.0f / (e + 1.0f);
}

// ---------------------------------------------------------------------------
// K1: sk[r] = sum_u v[u] * tanh( sum_c key[r,c] * Wq[u,c] )   (MFMA f16)
// 512 blocks x 256 thr (4 waves), 2 blocks/CU. Tile: 64 rows x 256 u.
// B: Wq converted f32->f16 IN-BLOCK into 64 KB LDS per 128-k phase
//    (Wq is 256 KB, L2-resident -> cheap redundant reads, no cvt kernel).
// A: global->register, lane(lx,lg) = row lx, k-slot lg (fragment-native).
// Inner kc loop is barrier-free.
// ---------------------------------------------------------------------------
__global__ __launch_bounds__(256, 2) void sk_mfma_kernel(
    const float* __restrict__ key, const float* __restrict__ Wq,
    const float* __restrict__ v, float* __restrict__ sk) {
  __shared__ _Float16 Bt[32768];  // 64 KB: [16 ks][256 u][8 j]

  const int tid = threadIdx.x;
  const int lane = tid & 63;
  const int wc = tid >> 6;   // wave 0..3 -> row group
  const int lx = lane & 15;
  const int lg = lane >> 4;
  const int arow = blockIdx.x * 64 + wc * 16 + lx;
  const float* gA = key + (size_t)arow * UD + lg * 8;

  f32x4 acc[16];
#pragma unroll
  for (int n = 0; n < 16; ++n) acc[n] = (f32x4){0.f, 0.f, 0.f, 0.f};

  for (int p = 0; p < 2; ++p) {
    // stage+convert B: 256 u rows x 128 k; thread tid = u, 16 ks iterations.
    {
      const float* wrow = Wq + (size_t)tid * UD + p * 128;
#pragma unroll
      for (int it = 0; it < 16; ++it) {
        const float4 w0 = *reinterpret_cast<const float4*>(wrow + it * 8);
        const float4 w1 = *reinterpret_cast<const float4*>(wrow + it * 8 + 4);
        f16x8 h;
        h[0] = (_Float16)w0.x; h[1] = (_Float16)w0.y;
        h[2] = (_Float16)w0.z; h[3] = (_Float16)w0.w;
        h[4] = (_Float16)w1.x; h[5] = (_Float16)w1.y;
        h[6] = (_Float16)w1.z; h[7] = (_Float16)w1.w;
        *reinterpret_cast<f16x8*>(Bt + ((size_t)it * 256 + tid) * 8) = h;
      }
    }
    __syncthreads();

#pragma unroll
    for (int kc = 0; kc < 4; ++kc) {
      const int k0 = p * 128 + kc * 32;
      const float4 a0 = *reinterpret_cast<const float4*>(gA + k0);
      const float4 a1 = *reinterpret_cast<const float4*>(gA + k0 + 4);
      f16x8 af;
      af[0] = (_Float16)a0.x; af[1] = (_Float16)a0.y;
      af[2] = (_Float16)a0.z; af[3] = (_Float16)a0.w;
      af[4] = (_Float16)a1.x; af[5] = (_Float16)a1.y;
      af[6] = (_Float16)a1.z; af[7] = (_Float16)a1.w;
#pragma unroll
      for (int n = 0; n < 16; ++n) {
        const f16x8 bf = *reinterpret_cast<const f16x8*>(
            Bt + (((kc * 4 + lg) * 256) + n * 16 + lx) * 8);
        acc[n] =
            __builtin_amdgcn_mfma_f32_16x16x32_f16(af, bf, acc[n], 0, 0, 0);
      }
    }
    __syncthreads();
  }

  // Epilogue: tanh, dot v over u=(n,lx), shfl-reduce over lx, store.
  // C layout: row_local = lg*4 + r, col(u_local) = lx.
  float out_r[4] = {0.f, 0.f, 0.f, 0.f};
#pragma unroll
  for (int n = 0; n < 16; ++n) {
    const float vn = v[n * 16 + lx];
#pragma unroll
    for (int r = 0; r < 4; ++r) out_r[r] += vn * fast_tanh(acc[n][r]);
  }
#pragma unroll
  for (int r = 0; r < 4; ++r) {
    float s = out_r[r];
    s += __shfl_xor(s, 1);
    s += __shfl_xor(s, 2);
    s += __shfl_xor(s, 4);
    s += __shfl_xor(s, 8);
    if (lx == 0) sk[blockIdx.x * 64 + wc * 16 + lg * 4 + r] = s;
  }
}

// ---------------------------------------------------------------------------
// K2: fused softmax + PV + broadcast, split over d.
// Block (b, dc): dc selects a 32-float (128 B = 1 cache line) d-slice.
//  1) compute masked-softmax weights wbuf[0..1023] for batch b (sk is L2-hot)
//  2) acc[dslice] = sum_k wbuf[k] * value[b,k,dslice]  (full-line reads)
//  3) write out[b,q,dslice] = acc for all q (broadcast over 1024 rows)
// grid = 32*8 = 256 blocks x 256 thr.
// ---------------------------------------------------------------------------
__global__ __launch_bounds__(256) void pv_bcast_kernel(
    const float* __restrict__ sk, const int* __restrict__ vlen,
    const float* __restrict__ value, float* __restrict__ out) {
  const int b = blockIdx.x >> 3;
  const int dc = blockIdx.x & 7;
  const int tid = threadIdx.x;
  const int vl = vlen[b];
  __shared__ float wbuf[1024];
  __shared__ float red4[8];
  __shared__ float racc[32][32];  // [kg][d_local]
  __shared__ float fin[32];
  const float* skb = sk + b * TK;

  if (vl == 0) {  // all scores equal fill -> uniform softmax
#pragma unroll
    for (int idx = 0; idx < 4; ++idx) wbuf[tid + idx * 256] = 1.0f / (float)TK;
  } else {
    float m = -1e30f;
#pragma unroll
    for (int idx = 0; idx < 4; ++idx) {
      const int k = tid + idx * 256;
      if (k < vl) m = fmaxf(m, skb[k]);
    }
    for (int off = 1; off < 64; off <<= 1) m = fmaxf(m, __shfl_xor(m, off));
    if ((tid & 63) == 0) red4[tid >> 6] = m;
    __syncthreads();
    m = fmaxf(fmaxf(red4[0], red4[1]), fmaxf(red4[2], red4[3]));
    float e[4];
    float zs = 0.f;
#pragma unroll
    for (int idx = 0; idx < 4; ++idx) {
      const int k = tid + idx * 256;
      e[idx] = (k < vl) ? __expf(skb[k] - m) : 0.f;
      zs += e[idx];
    }
    for (int off = 1; off < 64; off <<= 1) zs += __shfl_xor(zs, off);
    if ((tid & 63) == 0) red4[4 + (tid >> 6)] = zs;
    __syncthreads();
    const float rz = 1.0f / (red4[4] + red4[5] + red4[6] + red4[7]);
#pragma unroll
    for (int idx = 0; idx < 4; ++idx) wbuf[tid + idx * 256] = e[idx] * rz;
  }
  __syncthreads();

  // PV over d-slice: thread (c = tid&7 -> float4 col, kg = tid>>3 -> k row).
  const int c = tid & 7;
  const int kg = tid >> 3;
  const float* vb = value + (size_t)b * TK * UD + dc * 32 + c * 4;
  float4 a = make_float4(0.f, 0.f, 0.f, 0.f);
#pragma unroll 8
  for (int i = 0; i < 32; ++i) {
    const int k = i * 32 + kg;
    const float wk = wbuf[k];
    const float4 x = *reinterpret_cast<const float4*>(vb + (size_t)k * UD);
    a.x = fmaf(wk, x.x, a.x);
    a.y = fmaf(wk, x.y, a.y);
    a.z = fmaf(wk, x.z, a.z);
    a.w = fmaf(wk, x.w, a.w);
  }
  racc[kg][c * 4 + 0] = a.x;
  racc[kg][c * 4 + 1] = a.y;
  racc[kg][c * 4 + 2] = a.z;
  racc[kg][c * 4 + 3] = a.w;
  __syncthreads();
  if (tid < 32) {
    float s = 0.f;
#pragma unroll
    for (int g = 0; g < 32; ++g) s += racc[g][tid];
    fin[tid] = s;
  }
  __syncthreads();

  // Broadcast: thread t writes float4 col (t&7), rows q = (t>>3) + 32*i.
  const float4 f4 = *reinterpret_cast<const float4*>(&fin[c * 4]);
  float* ob = out + (size_t)b * TQ * UD + dc * 32 + c * 4;
#pragma unroll 8
  for (int i = 0; i < 32; ++i) {
    const int q = i * 32 + kg;
    *reinterpret_cast<float4*>(ob + (size_t)q * UD) = f4;
  }
}

// ---------------------------------------------------------------------------
extern "C" void kernel_launch(void* const* d_in, const int* in_sizes, int n_in,
                              void* d_out, int out_size, void* d_ws,
                              size_t ws_size, hipStream_t stream) {
  // inputs: 0 query, 1 key, 2 value, 3 valid_length, 4 W_k, 5 W_q, 6 v
  const float* key = (const float*)d_in[1];
  const float* value = (const float*)d_in[2];
  const int* vlen = (const int*)d_in[3];
  const float* Wq = (const float*)d_in[5];
  const float* v = (const float*)d_in[6];
  float* out = (float*)d_out;

  float* sk = (float*)d_ws;  // 32768 f32 = 128 KB

  sk_mfma_kernel<<<(NB * TK) / 64, 256, 0, stream>>>(key, Wq, v, sk);
  pv_bcast_kernel<<<NB * 8, 256, 0, stream>>>(sk, vlen, value, out);
}

// Round 7
// 43.240 us; speedup vs baseline: 2.7551x; 1.0127x over previous
//
#include <hip/hip_runtime.h>
#include <hip/hip_fp16.h>
#include <math.h>

// (B,Tq,Tk,U) = (32,1024,1024,256), f32 in/out.
#define NB 32
#define TQ 1024
#define TK 1024
#define UD 256

typedef __attribute__((ext_vector_type(8))) _Float16 f16x8;
typedef __attribute__((ext_vector_type(4))) float f32x4;

__device__ __forceinline__ float fast_tanh(float x) {
  const float e = __expf(2.0f * x);
  return 1.0f - 2.0f / (e + 1.0f);
}

__device__ __forceinline__ f16x8 cvt2(const float4 a, const float4 b) {
  f16x8 h;
  h[0] = (_Float16)a.x; h[1] = (_Float16)a.y;
  h[2] = (_Float16)a.z; h[3] = (_Float16)a.w;
  h[4] = (_Float16)b.x; h[5] = (_Float16)b.y;
  h[6] = (_Float16)b.z; h[7] = (_Float16)b.w;
  return h;
}

// ---------------------------------------------------------------------------
// K1: sk[r] = sum_u v[u] * tanh( sum_c key[r,c] * Wq[u,c] )   (MFMA f16)
// 512 blocks x 512 thr (8 waves, 2M x 4N). 64 rows/block, 256 u.
// K processed in 4 phases of 64; per phase both A (key) and B (Wq) tiles are
// converted f32->f16 into LDS (A 8 KB, B 32 KB -> 40 KB total).
// __launch_bounds__(512,4): 2 blocks/CU (4 waves/SIMD) for latency hiding.
// ---------------------------------------------------------------------------
__global__ __launch_bounds__(512, 4) void sk_mfma_kernel(
    const float* __restrict__ key, const float* __restrict__ Wq,
    const float* __restrict__ v, float* __restrict__ sk) {
  __shared__ _Float16 Bt[8 * 256 * 8];  // 32 KB [ks][u][8]
  __shared__ _Float16 At[8 * 64 * 8];   // 8 KB  [ks][r][8]

  const int tid = threadIdx.x;
  const int lane = tid & 63;
  const int wid = tid >> 6;  // 0..7
  const int wr = wid >> 2;   // 0..1 (row half)
  const int wc = wid & 3;    // 0..3 (u quarter)
  const int lx = lane & 15;
  const int lg = lane >> 4;
  const int row0 = blockIdx.x * 64;

  // staging assignments
  const int ar = tid & 63, ah = tid >> 6;     // A: row, k-slot
  const int bu = tid & 255, bg = tid >> 8;    // B: u row, ks half

  f32x4 acc[2][4];
#pragma unroll
  for (int m = 0; m < 2; ++m)
#pragma unroll
    for (int n = 0; n < 4; ++n) acc[m][n] = (f32x4){0.f, 0.f, 0.f, 0.f};

  for (int p = 0; p < 4; ++p) {
    const int k0 = p * 64;
    // ---- stage A: 64 rows x 64 k ----
    {
      const float* ga = key + (size_t)(row0 + ar) * UD + k0 + ah * 8;
      const float4 a0 = *reinterpret_cast<const float4*>(ga);
      const float4 a1 = *reinterpret_cast<const float4*>(ga + 4);
      *reinterpret_cast<f16x8*>(At + ((ah << 6) + ar) * 8) = cvt2(a0, a1);
    }
    // ---- stage B: 256 u x 64 k ----
    {
      const float* gb = Wq + (size_t)bu * UD + k0 + bg * 32;
#pragma unroll
      for (int gg = 0; gg < 4; ++gg) {
        const float4 b0 = *reinterpret_cast<const float4*>(gb + gg * 8);
        const float4 b1 = *reinterpret_cast<const float4*>(gb + gg * 8 + 4);
        const int ks = bg * 4 + gg;
        *reinterpret_cast<f16x8*>(Bt + ((ks << 8) + bu) * 8) = cvt2(b0, b1);
      }
    }
    __syncthreads();

#pragma unroll
    for (int kc = 0; kc < 2; ++kc) {
      const int ks = kc * 4 + lg;
      f16x8 af[2], bf[4];
#pragma unroll
      for (int m = 0; m < 2; ++m)
        af[m] = *reinterpret_cast<const f16x8*>(
            At + ((ks << 6) + wr * 32 + m * 16 + lx) * 8);
#pragma unroll
      for (int n = 0; n < 4; ++n)
        bf[n] = *reinterpret_cast<const f16x8*>(
            Bt + ((ks << 8) + wc * 64 + n * 16 + lx) * 8);
#pragma unroll
      for (int m = 0; m < 2; ++m)
#pragma unroll
        for (int n = 0; n < 4; ++n)
          acc[m][n] = __builtin_amdgcn_mfma_f32_16x16x32_f16(af[m], bf[n],
                                                             acc[m][n], 0, 0, 0);
    }
    __syncthreads();
  }

  // Epilogue: tanh, dot v over u=(n,lx), shfl-reduce over lx, LDS-reduce wc.
  // acc[m][n] reg r: row = wr*32 + m*16 + lg*4 + r ; u = wc*64 + n*16 + lx
  float vv[4];
#pragma unroll
  for (int n = 0; n < 4; ++n) vv[n] = v[wc * 64 + n * 16 + lx];

  float* red = (float*)At;  // [64][4]; safe after final barrier above
  float part[2][4];
#pragma unroll
  for (int m = 0; m < 2; ++m)
#pragma unroll
    for (int r = 0; r < 4; ++r) part[m][r] = 0.f;
#pragma unroll
  for (int m = 0; m < 2; ++m)
#pragma unroll
    for (int n = 0; n < 4; ++n)
#pragma unroll
      for (int r = 0; r < 4; ++r)
        part[m][r] += vv[n] * fast_tanh(acc[m][n][r]);

#pragma unroll
  for (int m = 0; m < 2; ++m)
#pragma unroll
    for (int r = 0; r < 4; ++r) {
      float s = part[m][r];
      s += __shfl_xor(s, 1);
      s += __shfl_xor(s, 2);
      s += __shfl_xor(s, 4);
      s += __shfl_xor(s, 8);
      if (lx == 0) red[(wr * 32 + m * 16 + lg * 4 + r) * 4 + wc] = s;
    }
  __syncthreads();
  if (tid < 64) {
    sk[row0 + tid] = red[tid * 4 + 0] + red[tid * 4 + 1] + red[tid * 4 + 2] +
                     red[tid * 4 + 3];
  }
}

// ---------------------------------------------------------------------------
// K2: fused softmax + PV + broadcast, split over d. 256 blocks x 1024 thr.
// Block (b, dc): 32-float (128 B line) d-slice.
//  1) masked-softmax weights for batch b (sk L2-hot, 1 k per thread)
//  2) acc = sum_k w[k]*value[b,k,dslice]  (128 kg-rows in flight)
//  3) out[b,q,dslice] = acc for all 1024 q
// ---------------------------------------------------------------------------
__global__ __launch_bounds__(1024) void pv_bcast_kernel(
    const float* __restrict__ sk, const int* __restrict__ vlen,
    const float* __restrict__ value, float* __restrict__ out) {
  const int b = blockIdx.x >> 3;
  const int dc = blockIdx.x & 7;
  const int tid = threadIdx.x;
  const int wid = tid >> 6;
  const int vl = vlen[b];
  __shared__ float wbuf[1024];
  __shared__ float redm[16];
  __shared__ float redz[16];
  __shared__ float racc[128][36];  // padded rows, 16B-aligned float4 slots
  __shared__ float fin2[8][32];
  __shared__ float fin[32];
  const float* skb = sk + b * TK;

  if (vl == 0) {  // all scores equal fill -> exactly uniform softmax
    wbuf[tid] = 1.0f / (float)TK;
  } else {
    const float s = skb[tid];
    const bool val = tid < vl;
    float m = val ? s : -1e30f;
    for (int off = 1; off < 64; off <<= 1) m = fmaxf(m, __shfl_xor(m, off));
    if ((tid & 63) == 0) redm[wid] = m;
    __syncthreads();
    m = redm[0];
#pragma unroll
    for (int w = 1; w < 16; ++w) m = fmaxf(m, redm[w]);
    const float e = val ? __expf(s - m) : 0.f;
    float zs = e;
    for (int off = 1; off < 64; off <<= 1) zs += __shfl_xor(zs, off);
    if ((tid & 63) == 0) redz[wid] = zs;
    __syncthreads();
    zs = redz[0];
#pragma unroll
    for (int w = 1; w < 16; ++w) zs += redz[w];
    wbuf[tid] = e * (1.0f / zs);
  }
  __syncthreads();

  // PV: c = tid&7 -> float4 col, kg = tid>>3 -> k row (128 rows in flight).
  const int c = tid & 7;
  const int kg = tid >> 3;
  const float* vb = value + (size_t)b * TK * UD + dc * 32 + c * 4;
  float4 a = make_float4(0.f, 0.f, 0.f, 0.f);
#pragma unroll
  for (int i = 0; i < 8; ++i) {
    const int k = i * 128 + kg;
    const float wk = wbuf[k];
    const float4 x = *reinterpret_cast<const float4*>(vb + (size_t)k * UD);
    a.x = fmaf(wk, x.x, a.x);
    a.y = fmaf(wk, x.y, a.y);
    a.z = fmaf(wk, x.z, a.z);
    a.w = fmaf(wk, x.w, a.w);
  }
  *reinterpret_cast<float4*>(&racc[kg][c * 4]) = a;
  __syncthreads();
  if (tid < 256) {
    const int d = tid & 31;
    const int g = tid >> 5;  // 0..7
    float s = 0.f;
#pragma unroll
    for (int j = 0; j < 16; ++j) s += racc[g * 16 + j][d];
    fin2[g][d] = s;
  }
  __syncthreads();
  if (tid < 32) {
    float s = 0.f;
#pragma unroll
    for (int g = 0; g < 8; ++g) s += fin2[g][tid];
    fin[tid] = s;
  }
  __syncthreads();

  // Broadcast: 128 q-rows in flight per iteration.
  const float4 f4 = *reinterpret_cast<const float4*>(&fin[c * 4]);
  float* ob = out + (size_t)b * TQ * UD + dc * 32 + c * 4;
  const int qg = tid >> 3;
#pragma unroll
  for (int i = 0; i < 8; ++i) {
    const int q = i * 128 + qg;
    *reinterpret_cast<float4*>(ob + (size_t)q * UD) = f4;
  }
}

// ---------------------------------------------------------------------------
extern "C" void kernel_launch(void* const* d_in, const int* in_sizes, int n_in,
                              void* d_out, int out_size, void* d_ws,
                              size_t ws_size, hipStream_t stream) {
  // inputs: 0 query, 1 key, 2 value, 3 valid_length, 4 W_k, 5 W_q, 6 v
  const float* key = (const float*)d_in[1];
  const float* value = (const float*)d_in[2];
  const int* vlen = (const int*)d_in[3];
  const float* Wq = (const float*)d_in[5];
  const float* v = (const float*)d_in[6];
  float* out = (float*)d_out;

  float* sk = (float*)d_ws;  // 32768 f32 = 128 KB

  sk_mfma_kernel<<<(NB * TK) / 64, 512, 0, stream>>>(key, Wq, v, sk);
  pv_bcast_kernel<<<NB * 8, 1024, 0, stream>>>(sk, vlen, value, out);
}